// Round 1
// baseline (124.069 us; speedup 1.0000x reference)
//
#include <hip/hip_runtime.h>

// Static shapes: B=16, T=512, D=384 (=96 float4), F=max_len=4096.
#define BB   16
#define TT   512
#define FF   4096
#define DD4  96
#define FPT  16                  // frames per gather block
#define TILES (FF / FPT)         // 256 tiles per batch
#define NTHR 256
#define NXCD 8

typedef float f4 __attribute__((ext_vector_type(4)));

// Kernel 1: one block per batch. Wave-level shfl scan (6 steps, 1 barrier)
// replaces the 18-barrier Hillis-Steele. The single __syncthreads also orders
// the -1 init stores before the scatter stores (same block, global fence).
__global__ __launch_bounds__(TT) void build_idx_kernel(
    const int* __restrict__ dur, int* __restrict__ fidx) {
    const int b = blockIdx.x;
    const int t = threadIdx.x;
    int* fb = fidx + b * FF;

#pragma unroll
    for (int k = 0; k < FF / TT; ++k) fb[k * TT + t] = -1;

    const int d = dur[b * TT + t];

    // intra-wave inclusive scan (64 lanes)
    int v = d;
#pragma unroll
    for (int off = 1; off < 64; off <<= 1) {
        int u = __shfl_up(v, off, 64);
        if ((t & 63) >= off) v += u;
    }

    __shared__ int wsum[TT / 64];          // 8 wave sums
    const int wid = t >> 6;
    if ((t & 63) == 63) wsum[wid] = v;
    __syncthreads();                       // orders init-before-scatter too

    int base = 0;
#pragma unroll
    for (int w = 0; w < TT / 64 - 1; ++w)
        if (w < wid) base += wsum[w];

    const int cum = v + base;              // inclusive cumsum
    const int start = cum - d;
    const int end = cum < FF ? cum : FF;   // max total = 512*7 = 3584 < 4096
    for (int f = start; f < end; ++f) fb[f] = t;
}

// Kernel 2: gather. Thread t owns frame (t>>4), columns (t&15)+16k.
//  - XCD-aware bijective swizzle: 4096 blocks, 8 XCDs -> XCD k gets a
//    contiguous 512-tile chunk = batches 2k,2k+1 (x working set 1.5 MB < 4 MB L2).
//  - Non-temporal stores: output is write-once; keep it out of L2 so L2
//    retains x and kills the read amplification from frame replication.
__global__ __launch_bounds__(NTHR) void gather_kernel(
    const f4* __restrict__ x, const int* __restrict__ fidx,
    f4* __restrict__ out) {
    int bid = blockIdx.x;
    bid = (bid & (NXCD - 1)) * (BB * TILES / NXCD) + (bid >> 3);  // bijective: 4096 % 8 == 0

    const int b    = bid / TILES;
    const int tile = bid - b * TILES;
    const int t    = threadIdx.x;
    const int fl   = t >> 4;               // frame within tile, 0..15
    const int c0   = t & 15;               // column group
    const int f    = tile * FPT + fl;

    const int idx = fidx[b * FF + f];
    f4* dst = out + ((size_t)b * FF + f) * DD4;

    if (idx >= 0) {
        const f4* src = x + ((size_t)b * TT + idx) * DD4;
#pragma unroll
        for (int k = 0; k < 6; ++k) {
            f4 v = src[c0 + 16 * k];                       // cached (L2-resident x)
            __builtin_nontemporal_store(v, &dst[c0 + 16 * k]);
        }
    } else {
        const f4 z = {0.f, 0.f, 0.f, 0.f};
#pragma unroll
        for (int k = 0; k < 6; ++k)
            __builtin_nontemporal_store(z, &dst[c0 + 16 * k]);
    }
}

extern "C" void kernel_launch(void* const* d_in, const int* in_sizes, int n_in,
                              void* d_out, int out_size, void* d_ws, size_t ws_size,
                              hipStream_t stream) {
    const float* x = (const float*)d_in[0];
    const int* dur = (const int*)d_in[1];   // int32 on device
    int* fidx = (int*)d_ws;                 // B*F ints = 256 KB scratch

    build_idx_kernel<<<BB, TT, 0, stream>>>(dur, fidx);
    gather_kernel<<<BB * TILES, NTHR, 0, stream>>>(
        (const f4*)x, fidx, (f4*)d_out);
}